// Round 17
// baseline (372.526 us; speedup 1.0000x reference)
//
#include <hip/hip_runtime.h>
#include <math.h>

#define CCH   50
#define HH    256
#define WW    256
#define BATCH 16
#define HSZ   64
#define WSZ   64
#define NTOP  240
#define SPX   66      // staged px per row (64 + 2 halo)
#define SROW  6       // staged rows (4 + 2 halo)

typedef __attribute__((ext_vector_type(8))) short s16x8;
typedef __attribute__((ext_vector_type(4))) float f32x4;

__device__ __forceinline__ unsigned short bf16rne(float x) {
  unsigned u = __float_as_uint(x);
  unsigned r = (u + 0x7FFFu + ((u >> 16) & 1u)) >> 16;
  return (unsigned short)r;
}
__device__ __forceinline__ float bf2f(unsigned short h) {
  return __uint_as_float(((unsigned)h) << 16);
}

// ---------------- Kernel 0: pack W1 into MFMA A-fragments (split bf16) ----
__global__ __launch_bounds__(64) void prep_wfrag_k(
    const float* __restrict__ W1, unsigned short* __restrict__ wf) {
  int combo = blockIdx.x;            // 0..143
  int lane = threadIdx.x;
  int sp = combo & 1;
  int t2 = combo >> 1;
  int mt = t2 & 3;
  int t3 = t2 >> 2;                  // 0..17
  int tap = t3 % 9;
  int chunk = t3 / 9;
  int co = mt * 16 + (lane & 15);
  int gbase = combo * 512 + lane * 8;
#pragma unroll
  for (int e = 0; e < 8; ++e) {
    int ci = chunk * 32 + ((lane >> 4) * 8) + e;
    float w = (co < CCH && ci < CCH) ? W1[co * (CCH * 9) + ci * 9 + tap] : 0.f;
    unsigned short h = bf16rne(w);
    unsigned short v = sp ? bf16rne(w - bf2f(h)) : h;
    wf[gbase + e] = v;
  }
}

// ---------------- Kernel 1: conv3x3 (50->50) + ReLU via MFMA -------------
// r17: 8 waves x 512 thr per tile (4 rows x 64 px); wave = 1 row x 64 px x
// 32 co (acc[2][4] = 32 AGPRs -> regs/wave ~halved -> 4 waves/SIMD target,
// 16 waves/CU vs 12). Stage phase runs on 512 threads (wall-time halves).
// Same products, same per-acc order as r11/r16 -> BIT-IDENTICAL output.
// 3-product split bf16 FROZEN (r9/r13: 2^-9 operand error flips topk).
__global__ __launch_bounds__(512, 4) void conv1_mfma_k(
    const float* __restrict__ in, const unsigned short* __restrict__ wf,
    const float* __restrict__ b1, float* __restrict__ x1p) {
  __shared__ alignas(16) short xlds[SROW * SPX * 64];   // 50,688 B

  int bx = blockIdx.x;
  int pq = bx & 3;                   // px quarter (64 px)
  int rg = (bx >> 2) & 63;           // row group (4 rows)
  int b  = bx >> 8;                  // batch
  int row0 = rg * 4;
  int px0g = pq * 64;

  int t = threadIdx.x;
  int lane = t & 63;
  int wv = t >> 6;                   // 0..7
  int wrow = wv >> 1;                // wave's output row (row0+wrow)
  int ch = wv & 1;                   // co half: [ch*32, ch*32+32)
  int ln15 = lane & 15;
  int lg = lane >> 4;

  f32x4 acc[2][4];                   // [mt][s]
#pragma unroll
  for (int mt = 0; mt < 2; ++mt)
#pragma unroll
    for (int s = 0; s < 4; ++s) acc[mt][s] = (f32x4){0.f, 0.f, 0.f, 0.f};

  const size_t in_b = ((size_t)b * CCH) << 16;

#pragma unroll
  for (int chunk = 0; chunk < 2; ++chunk) {
    __syncthreads();                 // previous chunk's reads complete
    // ---- stage: item = (row, oct, px); lane loads 8 ci for one px ----
    for (int i = t; i < SROW * 4 * SPX; i += 512) {   // 1584 items, 512 thr
      int ro = i / SPX;              // row*4 + oct
      int px = i - ro * SPX;
      int row = ro >> 2, oct = ro & 3;
      int gr = row0 - 1 + row;
      int gx = px0g - 1 + px;
      bool okxy = (gr >= 0 && gr < HH && gx >= 0 && gx < WW);
      const float* gp = in + in_b + ((size_t)(chunk * 32 + oct * 8) << 16)
                        + (gr << 8) + gx;
      unsigned hs[8], ls[8];
#pragma unroll
      for (int e = 0; e < 8; ++e) {
        int ci = chunk * 32 + oct * 8 + e;
        float x = (okxy && ci < CCH) ? gp[(size_t)e << 16] : 0.f;
        unsigned u = __float_as_uint(x);
        unsigned hu = u & 0xFFFF0000u;          // trunc-split hi
        float lo = x - __uint_as_float(hu);     // exact residual
        unsigned ul = __float_as_uint(lo);
        hs[e] = hu >> 16;
        ls[e] = (ul + 0x7FFFu + ((ul >> 16) & 1u)) >> 16;   // rne lo
      }
      s16x8 hv, lv;
#pragma unroll
      for (int e = 0; e < 8; ++e) { hv[e] = (short)hs[e]; lv[e] = (short)ls[e]; }
      int swz = (px & 7) << 3;                  // 16B-granule XOR (8 shorts)
      int base_sh = (row * SPX + px) * 64;
      *(s16x8*)&xlds[base_sh + ((oct * 8) ^ swz)] = hv;
      *(s16x8*)&xlds[base_sh + ((32 + oct * 8) ^ swz)] = lv;
    }
    __syncthreads();

    // ---- 9 taps ----
#pragma unroll
    for (int tap = 0; tap < 9; ++tap) {
      const int dh = tap / 3 - 1;
      const int dw = tap % 3 - 1;
      s16x8 ah[2], al[2];
#pragma unroll
      for (int mt = 0; mt < 2; ++mt) {
        int cb = ((chunk * 9 + tap) * 4 + ch * 2 + mt) * 2;
        ah[mt] = *(const s16x8*)(wf + (size_t)cb * 512 + lane * 8);
        al[mt] = *(const s16x8*)(wf + (size_t)(cb + 1) * 512 + lane * 8);
      }
      int rbase = (wrow + 1 + dh) * (SPX * 64);
#pragma unroll
      for (int s = 0; s < 4; ++s) {
        int pixL = 1 + s * 16 + ln15 + dw;
        int bsh = rbase + pixL * 64;
        int swz = (pixL & 7) << 3;
        s16x8 bh = *(const s16x8*)&xlds[bsh + ((lg * 8) ^ swz)];
        s16x8 bl = *(const s16x8*)&xlds[bsh + ((32 + lg * 8) ^ swz)];
        __builtin_amdgcn_s_setprio(1);
#pragma unroll
        for (int mt = 0; mt < 2; ++mt) {
          acc[mt][s] = __builtin_amdgcn_mfma_f32_16x16x32_bf16(
              ah[mt], bh, acc[mt][s], 0, 0, 0);
          acc[mt][s] = __builtin_amdgcn_mfma_f32_16x16x32_bf16(
              ah[mt], bl, acc[mt][s], 0, 0, 0);
          acc[mt][s] = __builtin_amdgcn_mfma_f32_16x16x32_bf16(
              al[mt], bh, acc[mt][s], 0, 0, 0);
        }
        __builtin_amdgcn_s_setprio(0);
      }
    }
  }

  // ---- epilogue: bias + ReLU -> planar f32 (C/D: col=lane&15,
  // row=(lane>>4)*4+reg) ----
  int orow = row0 + wrow;
#pragma unroll
  for (int s = 0; s < 4; ++s) {
    int px = px0g + s * 16 + ln15;
#pragma unroll
    for (int mt = 0; mt < 2; ++mt) {
#pragma unroll
      for (int reg = 0; reg < 4; ++reg) {
        int co = ch * 32 + mt * 16 + lg * 4 + reg;
        if (co < CCH) {
          float v = fmaxf(acc[mt][s][reg] + b1[co], 0.f);
          x1p[(((size_t)b * CCH + co) << 16) + (orow << 8) + px] = v;
        }
      }
    }
  }
}

// ---------------- Kernel 2: conv3x3 (50->2) + softmax[:,1] + 4x4 pool ----
// r16-exact branchless body (measured ~78 us).
__global__ __launch_bounds__(256) void conv2_pool_k(
    const float* __restrict__ x1p, const float* __restrict__ w2,
    const float* __restrict__ b2, float* __restrict__ pool) {
  int pb = blockIdx.x;                       // 1024 blocks = 8 XCD x 128
  int l = (pb & 7) * 128 + (pb >> 3);        // bijective chunked swizzle
  int b  = l >> 6;
  int rg = l & 63;
  int row0 = rg * 4;
  int px = threadIdx.x;

  float a0, a1, a2, a3, c0, c1, c2, c3;      // ch0 / ch1 per output row
  a0 = a1 = a2 = a3 = b2[0];
  c0 = c1 = c2 = c3 = b2[1];

  bool wm = px > 0, wp = px < WW - 1;
  int pxl = wm ? px - 1 : 0;                 // clamped, always valid
  int pxr = wp ? px + 1 : px;

  int   roff[6];                             // clamped row offsets (floats)
  float rvf[6];                              // 1.0 valid / 0.0 pad row
#pragma unroll
  for (int r = 0; r < 6; ++r) {
    int gr = row0 - 1 + r;
    rvf[r]  = (gr >= 0 && gr < HH) ? 1.f : 0.f;
    int grc = gr < 0 ? 0 : (gr > HH - 1 ? HH - 1 : gr);
    roff[r] = grc << 8;
  }

  const float* xb = x1p + (((size_t)b * CCH) << 16);

#define TAPX(T, A, C, LF, MM, RT) { \
    A = fmaf(wc0[3 * (T)], LF, A); A = fmaf(wc0[3 * (T) + 1], MM, A); \
    A = fmaf(wc0[3 * (T) + 2], RT, A); \
    C = fmaf(wc1[3 * (T)], LF, C); C = fmaf(wc1[3 * (T) + 1], MM, C); \
    C = fmaf(wc1[3 * (T) + 2], RT, C); }

#pragma unroll 2
  for (int ci = 0; ci < CCH; ++ci) {
    const float* xp = xb + ((size_t)ci << 16);
    float M[6], L[6], R[6];
#pragma unroll
    for (int r = 0; r < 6; ++r) {
      float mr = xp[roff[r] + px];
      float lr = xp[roff[r] + pxl];
      float rr = xp[roff[r] + pxr];
      M[r] = mr * rvf[r];
      L[r] = wm ? lr * rvf[r] : 0.f;
      R[r] = wp ? rr * rvf[r] : 0.f;
    }
    const float* wc0 = w2 + ci * 9;
    const float* wc1 = w2 + 450 + ci * 9;
    TAPX(0, a0, c0, L[0], M[0], R[0])
    TAPX(0, a1, c1, L[1], M[1], R[1]) TAPX(1, a0, c0, L[1], M[1], R[1])
    TAPX(0, a2, c2, L[2], M[2], R[2]) TAPX(1, a1, c1, L[2], M[2], R[2])
    TAPX(2, a0, c0, L[2], M[2], R[2])
    TAPX(0, a3, c3, L[3], M[3], R[3]) TAPX(1, a2, c2, L[3], M[3], R[3])
    TAPX(2, a1, c1, L[3], M[3], R[3])
    TAPX(1, a3, c3, L[4], M[4], R[4]) TAPX(2, a2, c2, L[4], M[4], R[4])
    TAPX(2, a3, c3, L[5], M[5], R[5])
  }
#undef TAPX

  float s = 1.f / (1.f + expf(a0 - c0)) + 1.f / (1.f + expf(a1 - c1))
          + 1.f / (1.f + expf(a2 - c2)) + 1.f / (1.f + expf(a3 - c3));
  s += __shfl_xor(s, 1);
  s += __shfl_xor(s, 2);
  if ((px & 3) == 0) {
    float p = s * (1.f / 16.f);
    pool[(size_t)b * 4096 + rg * 64 + (px >> 2)] = (p >= 0.f) ? p : 0.1f * p;
  }
}

// ---------------- Kernel 3: mix (25-tap) + per-batch top-240 sort --------
__global__ __launch_bounds__(1024) void mixtopk_k(
    const float* __restrict__ pool, const float* __restrict__ wk,
    const float* __restrict__ bk, float* __restrict__ mask_out,
    float* __restrict__ ob, float* __restrict__ oh, float* __restrict__ ow,
    int* __restrict__ idx_ws) {
  __shared__ unsigned long long keys[4096];
  __shared__ int sidx[256];
  int b = blockIdx.x, t = threadIdx.x;

  const float* pb = pool + (size_t)b * 4096;
  for (int i = t; i < 4096; i += 1024) {
    int hs = i >> 6, ws = i & 63;
    float c = pb[i];
    float s = 0.f;
#pragma unroll
    for (int ki = 0; ki < 5; ++ki) {
#pragma unroll
      for (int kj = 0; kj < 5; ++kj) {
        int y = hs + ki - 2, x = ws + kj - 2;
        float win = (y >= 0 && y < HSZ && x >= 0 && x < WSZ)
                        ? pb[y * WSZ + x] : 0.f;
        int k = ki * 5 + kj;
        s += (wk[k] * c + bk[k]) * win;
      }
    }
    mask_out[(size_t)b * 4096 + i] = s;
    unsigned u = __float_as_uint(s);
    u = (u & 0x80000000u) ? ~u : (u | 0x80000000u);   // order-preserving
    u = ~u;                                            // ascending -> desc
    keys[i] = ((unsigned long long)u << 12) | (unsigned)i;
  }
  __syncthreads();

  for (int k = 2; k <= 4096; k <<= 1) {
    for (int j = k >> 1; j > 0; j >>= 1) {
      for (int m = t; m < 2048; m += 1024) {
        int i = ((m & ~(j - 1)) << 1) | (m & (j - 1));
        int l = i | j;
        bool up = ((i & k) == 0);
        unsigned long long a = keys[i], c = keys[l];
        if ((a > c) == up) { keys[i] = c; keys[l] = a; }
      }
      __syncthreads();
    }
  }

  if (t < 256) sidx[t] = (t < NTOP) ? (int)(keys[t] & 0xFFFu) : 0x7FFFFFFF;
  __syncthreads();
  for (int k = 2; k <= 256; k <<= 1) {
    for (int j = k >> 1; j > 0; j >>= 1) {
      if (t < 128) {
        int i = ((t & ~(j - 1)) << 1) | (t & (j - 1));
        int l = i | j;
        bool up = ((i & k) == 0);
        int a = sidx[i], c = sidx[l];
        if ((a > c) == up) { sidx[i] = c; sidx[l] = a; }
      }
      __syncthreads();
    }
  }

  if (t < NTOP) {
    int id = sidx[t];
    int o = b * NTOP + t;
    ob[o] = (float)b;
    oh[o] = (float)(id >> 6);
    ow[o] = (float)(id & 63);
    idx_ws[o] = id;
  }
}

// ---------------- Kernel 4: gather 6x6 patches (pad=1, stride=4) ---------
__global__ __launch_bounds__(256) void gather_patch_k(
    const float* __restrict__ in, const int* __restrict__ idx_ws,
    float* __restrict__ patches) {
  int p = blockIdx.x;
  int b = p / NTOP;
  int id = idx_ws[p];
  int h = id >> 6, w = id & 63;
  int y0 = h * 4 - 1, x0 = w * 4 - 1;
  const float* base = in + (size_t)b * CCH * 65536;
  float* op = patches + (size_t)p * (CCH * 36);
  for (int e = threadIdx.x; e < CCH * 36; e += 256) {
    int c = e / 36;
    int r = (e - c * 36) / 6;
    int col = e - c * 36 - r * 6;
    int y = y0 + r, x = x0 + col;
    float v = 0.f;
    if (y >= 0 && y < HH && x >= 0 && x < WW)
      v = base[(size_t)c * 65536 + y * WW + x];
    op[e] = v;
  }
}

extern "C" void kernel_launch(void* const* d_in, const int* in_sizes, int n_in,
                              void* d_out, int out_size, void* d_ws, size_t ws_size,
                              hipStream_t stream) {
  const float* out_lr = (const float*)d_in[0];
  const float* W1 = (const float*)d_in[1];
  const float* b1 = (const float*)d_in[2];
  const float* W2 = (const float*)d_in[3];
  const float* b2 = (const float*)d_in[4];
  const float* Wk = (const float*)d_in[5];
  const float* bk = (const float*)d_in[6];

  float* x1p  = (float*)d_ws;                 // 16*50*256*256 f32
  float* pool = x1p + (size_t)52428800;       // 16*64*64
  int*  idxb  = (int*)(pool + 65536);         // 16*240
  unsigned short* wfrag = (unsigned short*)(pool + 65536 + 3840);  // 73,728 bf16

  float* out    = (float*)d_out;
  float* o_patch = out;                        // 3840*50*36
  float* o_b    = out + (size_t)6912000;
  float* o_h    = o_b + 3840;
  float* o_w    = o_h + 3840;
  float* o_mask = o_w + 3840;                  // 16*4096

  prep_wfrag_k<<<144, 64, 0, stream>>>(W1, wfrag);
  conv1_mfma_k<<<BATCH * 64 * 4, 512, 0, stream>>>(out_lr, wfrag, b1, x1p);
  conv2_pool_k<<<BATCH * 64, 256, 0, stream>>>(x1p, W2, b2, pool);
  mixtopk_k<<<BATCH, 1024, 0, stream>>>(pool, Wk, bk, o_mask, o_b, o_h, o_w, idxb);
  gather_patch_k<<<BATCH * NTOP, 256, 0, stream>>>(out_lr, idxb, o_patch);
}

// Round 18
// 361.563 us; speedup vs baseline: 1.0303x; 1.0303x over previous
//
#include <hip/hip_runtime.h>
#include <math.h>

#define CCH   50
#define HH    256
#define WW    256
#define BATCH 16
#define HSZ   64
#define WSZ   64
#define NTOP  240
#define SPX   66      // staged px per row (64 + 2 halo)
#define SROW  6       // staged rows (4 + 2 halo)

typedef __attribute__((ext_vector_type(8))) short s16x8;
typedef __attribute__((ext_vector_type(4))) float f32x4;

__device__ __forceinline__ unsigned short bf16rne(float x) {
  unsigned u = __float_as_uint(x);
  unsigned r = (u + 0x7FFFu + ((u >> 16) & 1u)) >> 16;
  return (unsigned short)r;
}
__device__ __forceinline__ float bf2f(unsigned short h) {
  return __uint_as_float(((unsigned)h) << 16);
}

// ---------------- Kernel 0: pack W1 into MFMA A-fragments (split bf16) ----
__global__ __launch_bounds__(64) void prep_wfrag_k(
    const float* __restrict__ W1, unsigned short* __restrict__ wf) {
  int combo = blockIdx.x;            // 0..143
  int lane = threadIdx.x;
  int sp = combo & 1;
  int t2 = combo >> 1;
  int mt = t2 & 3;
  int t3 = t2 >> 2;                  // 0..17
  int tap = t3 % 9;
  int chunk = t3 / 9;
  int co = mt * 16 + (lane & 15);
  int gbase = combo * 512 + lane * 8;
#pragma unroll
  for (int e = 0; e < 8; ++e) {
    int ci = chunk * 32 + ((lane >> 4) * 8) + e;
    float w = (co < CCH && ci < CCH) ? W1[co * (CCH * 9) + ci * 9 + tap] : 0.f;
    unsigned short h = bf16rne(w);
    unsigned short v = sp ? bf16rne(w - bf2f(h)) : h;
    wf[gbase + e] = v;
  }
}

// ---------------- Kernel 1: conv3x3 (50->50) + ReLU via MFMA -------------
// r11/r16-exact (measured 244 us): 16x16x32, 4 rows x 64 px, 4 waves, XOR
// swizzle, 3-product split bf16 (FROZEN — r9/r13: 2^-9 operand error flips
// topk), setprio around MFMA. Output PLANAR f32 x1p[b][co][row][px].
// Defended ceiling: r12 (32x32 shape, -43us), r13 (2-product, topk flip),
// r14 (reg prefetch, scratch spill), r17 (8-wave split, occupancy-neutral).
__global__ __launch_bounds__(256, 3) void conv1_mfma_k(
    const float* __restrict__ in, const unsigned short* __restrict__ wf,
    const float* __restrict__ b1, float* __restrict__ x1p) {
  __shared__ alignas(16) short xlds[SROW * SPX * 64];   // 50,688 B

  int bx = blockIdx.x;
  int pq = bx & 3;                   // px quarter (64 px)
  int rg = (bx >> 2) & 63;           // row group (4 rows)
  int b  = bx >> 8;                  // batch
  int row0 = rg * 4;
  int px0g = pq * 64;

  int t = threadIdx.x;
  int lane = t & 63;
  int wv = t >> 6;                   // wave owns output row row0+wv
  int ln15 = lane & 15;
  int lg = lane >> 4;

  f32x4 acc[4][4];                   // [mt][s]
#pragma unroll
  for (int mt = 0; mt < 4; ++mt)
#pragma unroll
    for (int s = 0; s < 4; ++s) acc[mt][s] = (f32x4){0.f, 0.f, 0.f, 0.f};

  const size_t in_b = ((size_t)b * CCH) << 16;

#pragma unroll
  for (int chunk = 0; chunk < 2; ++chunk) {
    __syncthreads();                 // previous chunk's reads complete
    // ---- stage: item = (row, oct, px); lane loads 8 ci for one px ----
    for (int i = t; i < SROW * 4 * SPX; i += 256) {   // 1584 items
      int ro = i / SPX;              // row*4 + oct
      int px = i - ro * SPX;
      int row = ro >> 2, oct = ro & 3;
      int gr = row0 - 1 + row;
      int gx = px0g - 1 + px;
      bool okxy = (gr >= 0 && gr < HH && gx >= 0 && gx < WW);
      const float* gp = in + in_b + ((size_t)(chunk * 32 + oct * 8) << 16)
                        + (gr << 8) + gx;
      unsigned hs[8], ls[8];
#pragma unroll
      for (int e = 0; e < 8; ++e) {
        int ci = chunk * 32 + oct * 8 + e;
        float x = (okxy && ci < CCH) ? gp[(size_t)e << 16] : 0.f;
        unsigned u = __float_as_uint(x);
        unsigned hu = u & 0xFFFF0000u;          // trunc-split hi
        float lo = x - __uint_as_float(hu);     // exact residual
        unsigned ul = __float_as_uint(lo);
        hs[e] = hu >> 16;
        ls[e] = (ul + 0x7FFFu + ((ul >> 16) & 1u)) >> 16;   // rne lo
      }
      s16x8 hv, lv;
#pragma unroll
      for (int e = 0; e < 8; ++e) { hv[e] = (short)hs[e]; lv[e] = (short)ls[e]; }
      int swz = (px & 7) << 3;                  // 16B-granule XOR (8 shorts)
      int base_sh = (row * SPX + px) * 64;
      *(s16x8*)&xlds[base_sh + ((oct * 8) ^ swz)] = hv;
      *(s16x8*)&xlds[base_sh + ((32 + oct * 8) ^ swz)] = lv;
    }
    __syncthreads();

    // ---- 9 taps ----
#pragma unroll
    for (int tap = 0; tap < 9; ++tap) {
      const int dh = tap / 3 - 1;
      const int dw = tap % 3 - 1;
      s16x8 ah[4], al[4];
#pragma unroll
      for (int mt = 0; mt < 4; ++mt) {
        int cb = ((chunk * 9 + tap) * 4 + mt) * 2;
        ah[mt] = *(const s16x8*)(wf + (size_t)cb * 512 + lane * 8);
        al[mt] = *(const s16x8*)(wf + (size_t)(cb + 1) * 512 + lane * 8);
      }
      int rbase = (wv + 1 + dh) * (SPX * 64);
#pragma unroll
      for (int s = 0; s < 4; ++s) {
        int pixL = 1 + s * 16 + ln15 + dw;
        int bsh = rbase + pixL * 64;
        int swz = (pixL & 7) << 3;
        s16x8 bh = *(const s16x8*)&xlds[bsh + ((lg * 8) ^ swz)];
        s16x8 bl = *(const s16x8*)&xlds[bsh + ((32 + lg * 8) ^ swz)];
        __builtin_amdgcn_s_setprio(1);
#pragma unroll
        for (int mt = 0; mt < 4; ++mt) {
          acc[mt][s] = __builtin_amdgcn_mfma_f32_16x16x32_bf16(
              ah[mt], bh, acc[mt][s], 0, 0, 0);
          acc[mt][s] = __builtin_amdgcn_mfma_f32_16x16x32_bf16(
              ah[mt], bl, acc[mt][s], 0, 0, 0);
          acc[mt][s] = __builtin_amdgcn_mfma_f32_16x16x32_bf16(
              al[mt], bh, acc[mt][s], 0, 0, 0);
        }
        __builtin_amdgcn_s_setprio(0);
      }
    }
  }

  // ---- epilogue: bias + ReLU -> planar f32 (C/D: col=lane&15,
  // row=(lane>>4)*4+reg) ----
  int orow = row0 + wv;
#pragma unroll
  for (int s = 0; s < 4; ++s) {
    int px = px0g + s * 16 + ln15;
#pragma unroll
    for (int mt = 0; mt < 4; ++mt) {
#pragma unroll
      for (int reg = 0; reg < 4; ++reg) {
        int co = mt * 16 + lg * 4 + reg;
        if (co < CCH) {
          float v = fmaxf(acc[mt][s][reg] + b1[co], 0.f);
          x1p[(((size_t)b * CCH + co) << 16) + (orow << 8) + px] = v;
        }
      }
    }
  }
}

// ---------------- Kernel 2: conv3x3 (50->2) + softmax[:,1] + 4x4 pool ----
// r16-exact branchless body (measured ~78 us, ~3.9 TB/s).
__global__ __launch_bounds__(256) void conv2_pool_k(
    const float* __restrict__ x1p, const float* __restrict__ w2,
    const float* __restrict__ b2, float* __restrict__ pool) {
  int pb = blockIdx.x;                       // 1024 blocks = 8 XCD x 128
  int l = (pb & 7) * 128 + (pb >> 3);        // bijective chunked swizzle
  int b  = l >> 6;
  int rg = l & 63;
  int row0 = rg * 4;
  int px = threadIdx.x;

  float a0, a1, a2, a3, c0, c1, c2, c3;      // ch0 / ch1 per output row
  a0 = a1 = a2 = a3 = b2[0];
  c0 = c1 = c2 = c3 = b2[1];

  bool wm = px > 0, wp = px < WW - 1;
  int pxl = wm ? px - 1 : 0;                 // clamped, always valid
  int pxr = wp ? px + 1 : px;

  int   roff[6];                             // clamped row offsets (floats)
  float rvf[6];                              // 1.0 valid / 0.0 pad row
#pragma unroll
  for (int r = 0; r < 6; ++r) {
    int gr = row0 - 1 + r;
    rvf[r]  = (gr >= 0 && gr < HH) ? 1.f : 0.f;
    int grc = gr < 0 ? 0 : (gr > HH - 1 ? HH - 1 : gr);
    roff[r] = grc << 8;
  }

  const float* xb = x1p + (((size_t)b * CCH) << 16);

#define TAPX(T, A, C, LF, MM, RT) { \
    A = fmaf(wc0[3 * (T)], LF, A); A = fmaf(wc0[3 * (T) + 1], MM, A); \
    A = fmaf(wc0[3 * (T) + 2], RT, A); \
    C = fmaf(wc1[3 * (T)], LF, C); C = fmaf(wc1[3 * (T) + 1], MM, C); \
    C = fmaf(wc1[3 * (T) + 2], RT, C); }

#pragma unroll 2
  for (int ci = 0; ci < CCH; ++ci) {
    const float* xp = xb + ((size_t)ci << 16);
    float M[6], L[6], R[6];
#pragma unroll
    for (int r = 0; r < 6; ++r) {
      float mr = xp[roff[r] + px];
      float lr = xp[roff[r] + pxl];
      float rr = xp[roff[r] + pxr];
      M[r] = mr * rvf[r];
      L[r] = wm ? lr * rvf[r] : 0.f;
      R[r] = wp ? rr * rvf[r] : 0.f;
    }
    const float* wc0 = w2 + ci * 9;
    const float* wc1 = w2 + 450 + ci * 9;
    TAPX(0, a0, c0, L[0], M[0], R[0])
    TAPX(0, a1, c1, L[1], M[1], R[1]) TAPX(1, a0, c0, L[1], M[1], R[1])
    TAPX(0, a2, c2, L[2], M[2], R[2]) TAPX(1, a1, c1, L[2], M[2], R[2])
    TAPX(2, a0, c0, L[2], M[2], R[2])
    TAPX(0, a3, c3, L[3], M[3], R[3]) TAPX(1, a2, c2, L[3], M[3], R[3])
    TAPX(2, a1, c1, L[3], M[3], R[3])
    TAPX(1, a3, c3, L[4], M[4], R[4]) TAPX(2, a2, c2, L[4], M[4], R[4])
    TAPX(2, a3, c3, L[5], M[5], R[5])
  }
#undef TAPX

  float s = 1.f / (1.f + expf(a0 - c0)) + 1.f / (1.f + expf(a1 - c1))
          + 1.f / (1.f + expf(a2 - c2)) + 1.f / (1.f + expf(a3 - c3));
  s += __shfl_xor(s, 1);
  s += __shfl_xor(s, 2);
  if ((px & 3) == 0) {
    float p = s * (1.f / 16.f);
    pool[(size_t)b * 4096 + rg * 64 + (px >> 2)] = (p >= 0.f) ? p : 0.1f * p;
  }
}

// ---------------- Kernel 3: mix (25-tap) + per-batch top-240 sort --------
__global__ __launch_bounds__(1024) void mixtopk_k(
    const float* __restrict__ pool, const float* __restrict__ wk,
    const float* __restrict__ bk, float* __restrict__ mask_out,
    float* __restrict__ ob, float* __restrict__ oh, float* __restrict__ ow,
    int* __restrict__ idx_ws) {
  __shared__ unsigned long long keys[4096];
  __shared__ int sidx[256];
  int b = blockIdx.x, t = threadIdx.x;

  const float* pb = pool + (size_t)b * 4096;
  for (int i = t; i < 4096; i += 1024) {
    int hs = i >> 6, ws = i & 63;
    float c = pb[i];
    float s = 0.f;
#pragma unroll
    for (int ki = 0; ki < 5; ++ki) {
#pragma unroll
      for (int kj = 0; kj < 5; ++kj) {
        int y = hs + ki - 2, x = ws + kj - 2;
        float win = (y >= 0 && y < HSZ && x >= 0 && x < WSZ)
                        ? pb[y * WSZ + x] : 0.f;
        int k = ki * 5 + kj;
        s += (wk[k] * c + bk[k]) * win;
      }
    }
    mask_out[(size_t)b * 4096 + i] = s;
    unsigned u = __float_as_uint(s);
    u = (u & 0x80000000u) ? ~u : (u | 0x80000000u);   // order-preserving
    u = ~u;                                            // ascending -> desc
    keys[i] = ((unsigned long long)u << 12) | (unsigned)i;
  }
  __syncthreads();

  for (int k = 2; k <= 4096; k <<= 1) {
    for (int j = k >> 1; j > 0; j >>= 1) {
      for (int m = t; m < 2048; m += 1024) {
        int i = ((m & ~(j - 1)) << 1) | (m & (j - 1));
        int l = i | j;
        bool up = ((i & k) == 0);
        unsigned long long a = keys[i], c = keys[l];
        if ((a > c) == up) { keys[i] = c; keys[l] = a; }
      }
      __syncthreads();
    }
  }

  if (t < 256) sidx[t] = (t < NTOP) ? (int)(keys[t] & 0xFFFu) : 0x7FFFFFFF;
  __syncthreads();
  for (int k = 2; k <= 256; k <<= 1) {
    for (int j = k >> 1; j > 0; j >>= 1) {
      if (t < 128) {
        int i = ((t & ~(j - 1)) << 1) | (t & (j - 1));
        int l = i | j;
        bool up = ((i & k) == 0);
        int a = sidx[i], c = sidx[l];
        if ((a > c) == up) { sidx[i] = c; sidx[l] = a; }
      }
      __syncthreads();
    }
  }

  if (t < NTOP) {
    int id = sidx[t];
    int o = b * NTOP + t;
    ob[o] = (float)b;
    oh[o] = (float)(id >> 6);
    ow[o] = (float)(id & 63);
    idx_ws[o] = id;
  }
}

// ---------------- Kernel 4: gather 6x6 patches (pad=1, stride=4) ---------
__global__ __launch_bounds__(256) void gather_patch_k(
    const float* __restrict__ in, const int* __restrict__ idx_ws,
    float* __restrict__ patches) {
  int p = blockIdx.x;
  int b = p / NTOP;
  int id = idx_ws[p];
  int h = id >> 6, w = id & 63;
  int y0 = h * 4 - 1, x0 = w * 4 - 1;
  const float* base = in + (size_t)b * CCH * 65536;
  float* op = patches + (size_t)p * (CCH * 36);
  for (int e = threadIdx.x; e < CCH * 36; e += 256) {
    int c = e / 36;
    int r = (e - c * 36) / 6;
    int col = e - c * 36 - r * 6;
    int y = y0 + r, x = x0 + col;
    float v = 0.f;
    if (y >= 0 && y < HH && x >= 0 && x < WW)
      v = base[(size_t)c * 65536 + y * WW + x];
    op[e] = v;
  }
}

extern "C" void kernel_launch(void* const* d_in, const int* in_sizes, int n_in,
                              void* d_out, int out_size, void* d_ws, size_t ws_size,
                              hipStream_t stream) {
  const float* out_lr = (const float*)d_in[0];
  const float* W1 = (const float*)d_in[1];
  const float* b1 = (const float*)d_in[2];
  const float* W2 = (const float*)d_in[3];
  const float* b2 = (const float*)d_in[4];
  const float* Wk = (const float*)d_in[5];
  const float* bk = (const float*)d_in[6];

  float* x1p  = (float*)d_ws;                 // 16*50*256*256 f32
  float* pool = x1p + (size_t)52428800;       // 16*64*64
  int*  idxb  = (int*)(pool + 65536);         // 16*240
  unsigned short* wfrag = (unsigned short*)(pool + 65536 + 3840);  // 73,728 bf16

  float* out    = (float*)d_out;
  float* o_patch = out;                        // 3840*50*36
  float* o_b    = out + (size_t)6912000;
  float* o_h    = o_b + 3840;
  float* o_w    = o_h + 3840;
  float* o_mask = o_w + 3840;                  // 16*4096

  prep_wfrag_k<<<144, 64, 0, stream>>>(W1, wfrag);
  conv1_mfma_k<<<BATCH * 64 * 4, 256, 0, stream>>>(out_lr, wfrag, b1, x1p);
  conv2_pool_k<<<BATCH * 64, 256, 0, stream>>>(x1p, W2, b2, pool);
  mixtopk_k<<<BATCH, 1024, 0, stream>>>(pool, Wk, bk, o_mask, o_b, o_h, o_w, idxb);
  gather_patch_k<<<BATCH * NTOP, 256, 0, stream>>>(out_lr, idxb, o_patch);
}